// Round 8
// baseline (381.787 us; speedup 1.0000x reference)
//
#include <hip/hip_runtime.h>

typedef __bf16 bf16x8 __attribute__((ext_vector_type(8)));
typedef float  f32x4  __attribute__((ext_vector_type(4)));
typedef float  f32x2  __attribute__((ext_vector_type(2)));

#define CSR_CAP 48    // padded-CSR slots/node; deg ~ Poisson(16); spill path covers any tail
#define CHUNK   4096  // edges per phase-1 block
#define NBUCK   256   // bucket = d >> 8

__device__ __forceinline__ float lrelu(float x, float s){ return x > 0.f ? x : s*x; }

// ---------------- prep: weights fp32 -> bf16 TRANSPOSED, S cast, flag detect, ovfn zero ----
__global__ void prep_k(const float* __restrict__ W1, const float* __restrict__ W2,
                       const float* __restrict__ W3, const float* __restrict__ S,
                       const int* __restrict__ ei,
                       __bf16* __restrict__ W1T, __bf16* __restrict__ W2T,
                       __bf16* __restrict__ W3T, __bf16* __restrict__ Sb,
                       int* __restrict__ flag, int* __restrict__ ovfn){
  int t = blockIdx.x*256 + threadIdx.x;
  if (t == 0){
    int is64 = 1;
    for (int k=1; k<64; k+=2) if (ei[k] != 0){ is64 = 0; break; }
    *flag = is64;
  }
  if (t == 1) *ovfn = 0;
  if (t < 16384){ int k = t>>7, n = t&127; W1T[n*128 + k] = (__bf16)W1[t]; }
  else if (t < 32768){ int i = t-16384; int k = i>>7, n = i&127; W2T[n*128 + k] = (__bf16)W2[i]; }
  else if (t < 40960){ int i = t-32768; int k = i>>6, n = i&63;  W3T[n*128 + k] = (__bf16)W3[i]; }
  else if (t < 73728){ int i = t-40960; Sb[i] = (__bf16)S[i]; }
}

// ---------------- GEMM body (used by layer-1 GEMM only) ----------------
// C[M,Ntot] = A[M,K] @ B; B pre-transposed as BTg[Ntot][K].
template<int K, bool AF32, bool ALPH, bool OUTBF>
__device__ __forceinline__ void gemm_body(int bx, int by,
        const __bf16* __restrict__ A, const float* __restrict__ Af,
        const __bf16* __restrict__ BTg,
        float* __restrict__ Cf, __bf16* __restrict__ Cb,
        const float* __restrict__ avs, const float* __restrict__ avd,
        float* __restrict__ as_, float* __restrict__ ad_,
        int M, int Ntot){
  constexpr int KP = K + 8;
  constexpr int KV = K / 8;
  __shared__ __align__(16) __bf16 BT[128*KP];
  const int n0 = by * 128;
  const int BN = min(128, Ntot - n0);
  const int tid = threadIdx.x;
  for (int idx = tid; idx < BN*KV; idx += 256){
    int nn = idx / KV, k8 = idx - nn*KV;
    *(bf16x8*)&BT[nn*KP + k8*8] = *(const bf16x8*)(BTg + (size_t)(n0+nn)*K + k8*8);
  }
  __syncthreads();
  const int lane = tid & 63, wave = tid >> 6;
  const int row0 = (bx*4 + wave) * 16;
  if (row0 >= M) return;
  const int m = lane & 15, kq = lane >> 4;
  bf16x8 af[K/32];
  if (AF32){
    const float* Ap = Af + (size_t)(row0 + m)*K + kq*8;
    #pragma unroll
    for (int ks=0; ks<K/32; ks++){
      f32x4 lo = *(const f32x4*)(Ap + ks*32);
      f32x4 hi = *(const f32x4*)(Ap + ks*32 + 4);
      bf16x8 v;
      #pragma unroll
      for (int j=0; j<4; j++){ v[j] = (__bf16)lo[j]; v[4+j] = (__bf16)hi[j]; }
      af[ks] = v;
    }
  } else {
    const __bf16* Ap = A + (size_t)(row0 + m)*K + kq*8;
    #pragma unroll
    for (int ks=0; ks<K/32; ks++) af[ks] = *(const bf16x8*)(Ap + ks*32);
  }
  float ps[4] = {0,0,0,0}, pd[4] = {0,0,0,0};
  const int ntc = BN >> 4;
  for (int nt=0; nt<ntc; nt++){
    f32x4 acc = {0.f, 0.f, 0.f, 0.f};
    const __bf16* Bp = &BT[(nt*16 + m)*KP + kq*8];
    #pragma unroll
    for (int ks=0; ks<K/32; ks++){
      bf16x8 bf = *(const bf16x8*)(Bp + ks*32);
      acc = __builtin_amdgcn_mfma_f32_16x16x32_bf16(af[ks], bf, acc, 0, 0, 0);
    }
    if (ALPH){
      float vs = avs[n0 + nt*16 + m], vd = avd[n0 + nt*16 + m];
      #pragma unroll
      for (int r=0; r<4; r++){ ps[r] += acc[r]*vs; pd[r] += acc[r]*vd; }
    }
    size_t cb = (size_t)(row0 + kq*4)*Ntot + (n0 + nt*16 + m);
    #pragma unroll
    for (int r=0; r<4; r++){
      if (OUTBF) Cb[cb + (size_t)r*Ntot] = (__bf16)acc[r];
      else       Cf[cb + (size_t)r*Ntot] = acc[r];
    }
  }
  if (ALPH){
    #pragma unroll
    for (int o=1; o<16; o<<=1){
      #pragma unroll
      for (int r=0; r<4; r++){ ps[r] += __shfl_xor(ps[r], o); pd[r] += __shfl_xor(pd[r], o); }
    }
    if (m == 0){
      #pragma unroll
      for (int r=0; r<4; r++){
        as_[row0 + kq*4 + r] = ps[r];
        ad_[row0 + kq*4 + r] = pd[r];
      }
    }
  }
}

// ---------------- fused: layer-1 GEMM (blocks < gx) || partition phase 1 (blocks >= gx) ----
__global__ __launch_bounds__(256) void gemm1_part1_k(
        const float* __restrict__ x, const __bf16* __restrict__ W1T,
        __bf16* __restrict__ hb, const float* __restrict__ a1s,
        const float* __restrict__ a1d, float* __restrict__ as_,
        float* __restrict__ ad_, int M,
        const int* __restrict__ ei, const int* __restrict__ flag, int E,
        int2* __restrict__ eb, int* __restrict__ choff, int* __restrict__ ccnt,
        int gx){
  if ((int)blockIdx.x < gx){
    gemm_body<128,true,true,true>(blockIdx.x, 0, nullptr, x, W1T, nullptr, hb,
                                  a1s, a1d, as_, ad_, M, 128);
    return;
  }
  __shared__ int cnt[NBUCK];
  __shared__ int sc[NBUCK];
  const int tid = threadIdx.x;
  const int blk = (int)blockIdx.x - gx;
  const int c0 = blk * CHUNK;
  const int c1 = min(c0 + CHUNK, E);
  const int f = *flag;
  const long long* e64 = (const long long*)ei;
  cnt[tid] = 0;
  __syncthreads();
  for (int t = c0 + tid; t < c1; t += 256){
    int d = f ? (int)e64[(long)E + t] : ei[(long)E + t];
    atomicAdd(&cnt[d >> 8], 1);                 // LDS
  }
  __syncthreads();
  sc[tid] = cnt[tid];
  __syncthreads();
  for (int d=1; d<NBUCK; d<<=1){
    int v = (tid >= d) ? sc[tid-d] : 0;
    __syncthreads();
    sc[tid] += v;
    __syncthreads();
  }
  const int excl = sc[tid] - cnt[tid];
  __syncthreads();
  sc[tid] = excl;
  choff[blk*NBUCK + tid] = c0 + excl;
  ccnt [blk*NBUCK + tid] = cnt[tid];
  __syncthreads();
  for (int t = c0 + tid; t < c1; t += 256){
    int s, d;
    if (f){ s = (int)e64[t]; d = (int)e64[(long)E + t]; }
    else  { s = ei[t];       d = ei[(long)E + t]; }
    int p = atomicAdd(&sc[d >> 8], 1);          // LDS
    eb[c0 + p] = make_int2(s, d);
  }
}

// ---------------- partition phase 2: one block per bucket; LDS rank -> padded CSR ----
__global__ __launch_bounds__(256) void part2_k(
        const int2* __restrict__ eb, const int* __restrict__ choff,
        const int* __restrict__ ccnt, int B1,
        int* __restrict__ cnt, int* __restrict__ csr,
        int* __restrict__ ovfn, int* __restrict__ ovf, int N){
  __shared__ int lcnt[256];
  const int tid = threadIdx.x;
  const int b = blockIdx.x;
  const int d0 = b << 8;
  lcnt[tid] = 0;
  __syncthreads();
  for (int c = tid; c < B1; c += 256){
    const int off = choff[c*NBUCK + b];
    const int k   = ccnt [c*NBUCK + b];
    for (int j=0; j<k; j++){
      const int2 e = eb[off + j];
      const int r = atomicAdd(&lcnt[e.y - d0], 1);   // LDS
      if (r < CSR_CAP) csr[(size_t)e.y*CSR_CAP + r] = e.x;
      else { int op = atomicAdd(ovfn, 1); ovf[2*op] = e.y; ovf[2*op+1] = e.x; }
    }
  }
  __syncthreads();
  const int d = d0 + tid;
  if (d < N) cnt[d] = lcnt[tid];
}

// ---------------- FUSED agg_L + gemm_{L+1} ----------------
// Block = 64 dst nodes. Phase A: 16-lane-group online-softmax aggregation (identical inner
// loop to the proven R5/R7 aggregate) writing bias+act'ed y rows into an LDS A-tile.
// Phase B: 64-row MFMA tile of the next GEMM, A from LDS, B fragments DIRECTLY from global
// (W is 16-64KB, L2-hot in every XCD -> no B staging, LDS stays small, occupancy preserved).
// 8 waves: wave w -> row-strip w>>1, nt-half w&1. Alpha epilogue combined via LDS.
// y never touches HBM; gemm MFMA hides under other blocks' gather latency.
template<int FIN, int ACT, bool ALPH, bool OUTBF>
__global__ __launch_bounds__(512) void fused_k(
        const __bf16* __restrict__ h,
        const float* __restrict__ as, const float* __restrict__ ad,
        const int* __restrict__ cnt, const int* __restrict__ csr,
        const int* __restrict__ ovfn, const int* __restrict__ ovf,
        const float* __restrict__ bias,
        const __bf16* __restrict__ BTg,
        __bf16* __restrict__ Cb, float* __restrict__ Cf,
        const float* __restrict__ avs, const float* __restrict__ avd,
        float* __restrict__ asO, float* __restrict__ adO,
        int N, int Ntot){
  constexpr int FPL = FIN/16;          // bf16 per lane (8 or 4)
  constexpr int DW  = FPL/2;           // dwords per lane
  constexpr int KP  = FIN + 8;         // LDS row pad
  __shared__ __align__(16) __bf16 A_lds[64*KP];
  __shared__ float aS[2][64], aD[2][64];
  __shared__ int2 sw[512];
  const int tid = threadIdx.x;
  const int l = tid & 15;
  const int gbase = tid & 0x1F0;
  const int row_blk = (int)blockIdx.x * 64;
  const int nov = *ovfn;

  union U2 { unsigned u[2]; f32x2 f; };

  // ---- phase A: aggregate 64 nodes (2 rounds x 32 groups) ----
  for (int r=0; r<2; r++){
    const int lr = r*32 + (tid>>4);
    const int i = row_blk + lr;
    if (i < N){
      const int deg = min(cnt[i], CSR_CAP);
      const long b0 = (long)i*CSR_CAP;
      const float adi = ad[i];
      const float e_self = lrelu(as[i] + adi, 0.2f);
      float m = e_self, dsum = 0.f;
      f32x2 acc2[DW];
      #pragma unroll
      for (int d=0; d<DW; d++) acc2[d] = (f32x2){0.f, 0.f};
      auto edge_fma = [&](int sk, float wk){
        if constexpr (DW == 4){
          const uint4 hv = *(const uint4*)(h + (size_t)sk*FIN + l*FPL);
          U2 t0,t1,t2,t3;
          t0.u[0]=hv.x<<16; t0.u[1]=hv.x&0xffff0000u;
          t1.u[0]=hv.y<<16; t1.u[1]=hv.y&0xffff0000u;
          t2.u[0]=hv.z<<16; t2.u[1]=hv.z&0xffff0000u;
          t3.u[0]=hv.w<<16; t3.u[1]=hv.w&0xffff0000u;
          acc2[0]+=wk*t0.f; acc2[1]+=wk*t1.f; acc2[2]+=wk*t2.f; acc2[3]+=wk*t3.f;
        } else {
          const uint2 hv = *(const uint2*)(h + (size_t)sk*FIN + l*FPL);
          U2 t0,t1;
          t0.u[0]=hv.x<<16; t0.u[1]=hv.x&0xffff0000u;
          t1.u[0]=hv.y<<16; t1.u[1]=hv.y&0xffff0000u;
          acc2[0]+=wk*t0.f; acc2[1]+=wk*t1.f;
        }
      };
      for (int base = 0; base < deg; base += 16){
        const int p = base + l;
        int s = 0; float e = -1e30f;
        if (p < deg){ s = csr[b0 + p]; e = lrelu(as[s] + adi, 0.2f); }
        float cm = e;
        #pragma unroll
        for (int o=8; o; o>>=1) cm = fmaxf(cm, __shfl_xor(cm, o));
        if (cm > m){                   // group-uniform
          const float scv = __expf(m - cm);
          #pragma unroll
          for (int d=0; d<DW; d++) acc2[d] *= scv;
          dsum *= scv; m = cm;
        }
        const float wv = (p < deg) ? __expf(e - m) : 0.f;
        dsum += wv;
        sw[tid] = make_int2(s, __float_as_int(wv));
        const int c = min(16, deg - base);
        if (c == 16){
          #pragma unroll
          for (int k=0; k<16; k++){ const int2 sk = sw[gbase+k]; edge_fma(sk.x, __int_as_float(sk.y)); }
        } else {
          for (int k=0; k<c; k++){ const int2 sk = sw[gbase+k]; edge_fma(sk.x, __int_as_float(sk.y)); }
        }
      }
      if (nov > 0){                    // spill path: correctness only, never hot
        for (int p=0; p<nov; p++){
          if (ovf[2*p] != i) continue;
          const int s = ovf[2*p+1];
          const float e = lrelu(as[s] + adi, 0.2f);
          if (e > m){
            const float scv = __expf(m - e);
            #pragma unroll
            for (int d=0; d<DW; d++) acc2[d] *= scv;
            dsum *= scv; m = e;
          }
          const float wv = __expf(e - m);
          if (l == 0) dsum += wv;      // counted once per group (group-sum follows)
          edge_fma(s, wv);
        }
      }
      #pragma unroll
      for (int o=8; o; o>>=1) dsum += __shfl_xor(dsum, o);
      const float wself = __expf(e_self - m);
      dsum += wself;
      edge_fma(i, wself);              // self loop
      const float inv = 1.f / dsum;
      __bf16 ov[FPL];
      #pragma unroll
      for (int j=0; j<FPL; j++){
        float o0 = acc2[j>>1][j&1]*inv + bias[l*FPL + j];
        if (ACT) o0 = lrelu(o0, 0.1f);
        ov[j] = (__bf16)o0;
      }
      if constexpr (FPL == 8) *(bf16x8*)&A_lds[lr*KP + l*8] = *(bf16x8*)ov;
      else                    *(uint2*)&A_lds[lr*KP + l*4] = *(uint2*)ov;
    }
  }
  __syncthreads();

  // ---- phase B: 64-row tile of the next GEMM (A from LDS, B from global/L2) ----
  const int lane = tid & 63, wave = tid >> 6;
  const int strip = wave >> 1, half = wave & 1;
  const int rowg = row_blk + strip*16;
  const int m = lane & 15, kq = lane >> 4;
  if (rowg < N){
    bf16x8 af[FIN/32];
    #pragma unroll
    for (int ks=0; ks<FIN/32; ks++)
      af[ks] = *(const bf16x8*)&A_lds[(strip*16 + m)*KP + kq*8 + ks*32];
    float ps[4] = {0,0,0,0}, pd[4] = {0,0,0,0};
    const int nth = Ntot >> 5;                 // tiles per half
    for (int nt = half*nth; nt < half*nth + nth; nt++){
      f32x4 acc = {0.f, 0.f, 0.f, 0.f};
      const __bf16* Bp = BTg + (size_t)(nt*16 + m)*FIN + kq*8;
      #pragma unroll
      for (int ks=0; ks<FIN/32; ks++){
        bf16x8 bf = *(const bf16x8*)(Bp + ks*32);
        acc = __builtin_amdgcn_mfma_f32_16x16x32_bf16(af[ks], bf, acc, 0, 0, 0);
      }
      if (ALPH){
        const float vs = avs[nt*16 + m], vd = avd[nt*16 + m];
        #pragma unroll
        for (int q=0; q<4; q++){ ps[q] += acc[q]*vs; pd[q] += acc[q]*vd; }
      }
      const size_t cb = (size_t)(rowg + kq*4)*Ntot + nt*16 + m;
      #pragma unroll
      for (int q=0; q<4; q++){
        if (OUTBF) Cb[cb + (size_t)q*Ntot] = (__bf16)acc[q];
        else       Cf[cb + (size_t)q*Ntot] = acc[q];
      }
    }
    if (ALPH){
      #pragma unroll
      for (int o=1; o<16; o<<=1){
        #pragma unroll
        for (int q=0; q<4; q++){ ps[q] += __shfl_xor(ps[q], o); pd[q] += __shfl_xor(pd[q], o); }
      }
      if (m == 0){
        #pragma unroll
        for (int q=0; q<4; q++){
          aS[half][strip*16 + kq*4 + q] = ps[q];
          aD[half][strip*16 + kq*4 + q] = pd[q];
        }
      }
    }
  }
  if (ALPH){
    __syncthreads();
    const int rr = row_blk + tid;
    if (tid < 64 && rr < N){
      asO[rr] = aS[0][tid] + aS[1][tid];
      adO[rr] = aD[0][tid] + aD[1][tid];
    }
  }
}

extern "C" void kernel_launch(void* const* d_in, const int* in_sizes, int n_in,
                              void* d_out, int out_size, void* d_ws, size_t ws_size,
                              hipStream_t stream){
  const float* x   = (const float*)d_in[0];
  const int*   ei  = (const int*)d_in[1];
  const float* W1  = (const float*)d_in[2];
  const float* a1s = (const float*)d_in[3];
  const float* a1d = (const float*)d_in[4];
  const float* b1  = (const float*)d_in[5];
  const float* W2  = (const float*)d_in[6];
  const float* a2s = (const float*)d_in[7];
  const float* a2d = (const float*)d_in[8];
  const float* b2  = (const float*)d_in[9];
  const float* W3  = (const float*)d_in[10];
  const float* a3s = (const float*)d_in[11];
  const float* a3d = (const float*)d_in[12];
  const float* b3  = (const float*)d_in[13];
  const float* S   = (const float*)d_in[14];
  float* out = (float*)d_out;            // fp32 output

  const int N = in_sizes[0] / 128;   // 50000
  const int E = in_sizes[1] / 2;     // 800000

  char* w = (char*)d_ws;
  size_t o = 0;
  auto alloc = [&](size_t bytes)->void*{
    void* p = w + o; o += bytes; o = (o + 255) & ~(size_t)255; return p;
  };
  const int B1 = (E + CHUNK - 1) / CHUNK;       // phase-1 blocks (196)
  int*    cnt    = (int*)   alloc((size_t)N*4);
  int*    csr    = (int*)   alloc((size_t)N*CSR_CAP*4);
  int2*   eb     = (int2*)  alloc((size_t)E*8);
  int*    choff  = (int*)   alloc((size_t)B1*NBUCK*4);
  int*    ccnt   = (int*)   alloc((size_t)B1*NBUCK*4);
  int*    ovfn   = (int*)   alloc(4);
  int*    ovf    = (int*)   alloc(65536);
  int*    flag   = (int*)   alloc(4);
  float*  as1    = (float*) alloc((size_t)N*4);
  float*  ad1    = (float*) alloc((size_t)N*4);
  float*  as2    = (float*) alloc((size_t)N*4);
  float*  ad2    = (float*) alloc((size_t)N*4);
  __bf16* hA     = (__bf16*)alloc((size_t)N*128*2);
  __bf16* hB     = (__bf16*)alloc((size_t)N*128*2);
  __bf16* W1T    = (__bf16*)alloc(128*128*2);
  __bf16* W2T    = (__bf16*)alloc(128*128*2);
  __bf16* W3T    = (__bf16*)alloc(64*128*2);
  __bf16* Sb     = (__bf16*)alloc(512*64*2);
  (void)ws_size; (void)n_in; (void)out_size;

  const int gx  = (N + 63) / 64;               // 782 gemm1 blocks
  const int nbk = (N + 255) / 256;             // phase-2 blocks
  const int gf  = (N + 63) / 64;               // fused blocks (64 nodes each)

  // K1: weight prep + flag detect + ovfn zero
  prep_k<<<288, 256, 0, stream>>>(W1, W2, W3, S, ei, W1T, W2T, W3T, Sb, flag, ovfn);
  // K2: layer-1 GEMM || partition phase 1 (independent halves, overlapped)
  gemm1_part1_k<<<gx + B1, 256, 0, stream>>>(
      x, W1T, hA, a1s, a1d, as1, ad1, N, ei, flag, E, eb, choff, ccnt, gx);
  // K3: partition phase 2 -> padded CSR + cnt
  part2_k<<<nbk, 256, 0, stream>>>(eb, choff, ccnt, B1, cnt, csr, ovfn, ovf, N);
  // K4: agg1 (from hA, L1 alphas) + gemm2 -> hB, L2 alphas
  fused_k<128,1,true,true><<<gf, 512, 0, stream>>>(
      hA, as1, ad1, cnt, csr, ovfn, ovf, b1, W2T, hB, nullptr,
      a2s, a2d, as2, ad2, N, 128);
  // K5: agg2 (from hB, L2 alphas) + gemm3 -> hA (Ntot=64), L3 alphas
  fused_k<128,1,true,true><<<gf, 512, 0, stream>>>(
      hB, as2, ad2, cnt, csr, ovfn, ovf, b2, W3T, hA, nullptr,
      a3s, a3d, as1, ad1, N, 64);
  // K6: agg3 (from hA, F=64, no act) + final projection out = y3 @ S^T (fp32)
  fused_k<64,0,false,false><<<gf, 512, 0, stream>>>(
      hA, as1, ad1, cnt, csr, ovfn, ovf, b3, Sb, nullptr, out,
      nullptr, nullptr, nullptr, nullptr, N, 512);
}

// Round 9
// 330.030 us; speedup vs baseline: 1.1568x; 1.1568x over previous
//
#include <hip/hip_runtime.h>

typedef __bf16 bf16x8 __attribute__((ext_vector_type(8)));
typedef float  f32x4  __attribute__((ext_vector_type(4)));
typedef float  f32x2  __attribute__((ext_vector_type(2)));

#define CSR_CAP 48    // padded-CSR slots/node; deg ~ Poisson(16); spill path covers any tail
#define CHUNK   4096  // edges per phase-1 block
#define NBUCK   256   // bucket = d >> 8

__device__ __forceinline__ float lrelu(float x, float s){ return x > 0.f ? x : s*x; }

// ---------------- prep: weights fp32 -> bf16 TRANSPOSED, S cast, flag detect, ovfn zero ----
__global__ void prep_k(const float* __restrict__ W1, const float* __restrict__ W2,
                       const float* __restrict__ W3, const float* __restrict__ S,
                       const int* __restrict__ ei,
                       __bf16* __restrict__ W1T, __bf16* __restrict__ W2T,
                       __bf16* __restrict__ W3T, __bf16* __restrict__ Sb,
                       int* __restrict__ flag, int* __restrict__ ovfn){
  int t = blockIdx.x*256 + threadIdx.x;
  if (t == 0){
    int is64 = 1;
    for (int k=1; k<64; k+=2) if (ei[k] != 0){ is64 = 0; break; }
    *flag = is64;
  }
  if (t == 1) *ovfn = 0;
  if (t < 16384){ int k = t>>7, n = t&127; W1T[n*128 + k] = (__bf16)W1[t]; }
  else if (t < 32768){ int i = t-16384; int k = i>>7, n = i&127; W2T[n*128 + k] = (__bf16)W2[i]; }
  else if (t < 40960){ int i = t-32768; int k = i>>6, n = i&63;  W3T[n*128 + k] = (__bf16)W3[i]; }
  else if (t < 73728){ int i = t-40960; Sb[i] = (__bf16)S[i]; }
}

// ---------------- GEMM body ----------------
// C[M,Ntot] = A[M,K] @ B; B pre-transposed as BTg[Ntot][K].
// A frag: A[m=lane&15][k=(lane>>4)*8+j]; B frag: BT[n=lane&15][k]; C/D: col=lane&15, row=(lane>>4)*4+reg.
template<int K, bool AF32, bool ALPH, bool OUTBF>
__device__ __forceinline__ void gemm_body(int bx, int by,
        const __bf16* __restrict__ A, const float* __restrict__ Af,
        const __bf16* __restrict__ BTg,
        float* __restrict__ Cf, __bf16* __restrict__ Cb,
        const float* __restrict__ avs, const float* __restrict__ avd,
        float* __restrict__ as_, float* __restrict__ ad_,
        int M, int Ntot){
  constexpr int KP = K + 8;
  constexpr int KV = K / 8;
  __shared__ __align__(16) __bf16 BT[128*KP];
  const int n0 = by * 128;
  const int BN = min(128, Ntot - n0);
  const int tid = threadIdx.x;
  for (int idx = tid; idx < BN*KV; idx += 256){
    int nn = idx / KV, k8 = idx - nn*KV;
    *(bf16x8*)&BT[nn*KP + k8*8] = *(const bf16x8*)(BTg + (size_t)(n0+nn)*K + k8*8);
  }
  __syncthreads();
  const int lane = tid & 63, wave = tid >> 6;
  const int row0 = (bx*4 + wave) * 16;
  if (row0 >= M) return;
  const int m = lane & 15, kq = lane >> 4;
  bf16x8 af[K/32];
  if (AF32){
    const float* Ap = Af + (size_t)(row0 + m)*K + kq*8;
    #pragma unroll
    for (int ks=0; ks<K/32; ks++){
      f32x4 lo = *(const f32x4*)(Ap + ks*32);
      f32x4 hi = *(const f32x4*)(Ap + ks*32 + 4);
      bf16x8 v;
      #pragma unroll
      for (int j=0; j<4; j++){ v[j] = (__bf16)lo[j]; v[4+j] = (__bf16)hi[j]; }
      af[ks] = v;
    }
  } else {
    const __bf16* Ap = A + (size_t)(row0 + m)*K + kq*8;
    #pragma unroll
    for (int ks=0; ks<K/32; ks++) af[ks] = *(const bf16x8*)(Ap + ks*32);
  }
  float ps[4] = {0,0,0,0}, pd[4] = {0,0,0,0};
  const int ntc = BN >> 4;
  for (int nt=0; nt<ntc; nt++){
    f32x4 acc = {0.f, 0.f, 0.f, 0.f};
    const __bf16* Bp = &BT[(nt*16 + m)*KP + kq*8];
    #pragma unroll
    for (int ks=0; ks<K/32; ks++){
      bf16x8 bf = *(const bf16x8*)(Bp + ks*32);
      acc = __builtin_amdgcn_mfma_f32_16x16x32_bf16(af[ks], bf, acc, 0, 0, 0);
    }
    if (ALPH){
      float vs = avs[n0 + nt*16 + m], vd = avd[n0 + nt*16 + m];
      #pragma unroll
      for (int r=0; r<4; r++){ ps[r] += acc[r]*vs; pd[r] += acc[r]*vd; }
    }
    size_t cb = (size_t)(row0 + kq*4)*Ntot + (n0 + nt*16 + m);
    #pragma unroll
    for (int r=0; r<4; r++){
      if (OUTBF) Cb[cb + (size_t)r*Ntot] = (__bf16)acc[r];
      else       Cf[cb + (size_t)r*Ntot] = acc[r];
    }
  }
  if (ALPH){
    #pragma unroll
    for (int o=1; o<16; o<<=1){
      #pragma unroll
      for (int r=0; r<4; r++){ ps[r] += __shfl_xor(ps[r], o); pd[r] += __shfl_xor(pd[r], o); }
    }
    if (m == 0){
      #pragma unroll
      for (int r=0; r<4; r++){
        as_[row0 + kq*4 + r] = ps[r];
        ad_[row0 + kq*4 + r] = pd[r];
      }
    }
  }
}

template<int K, bool AF32, bool ALPH, bool OUTBF>
__global__ __launch_bounds__(256) void gemm_k(const __bf16* __restrict__ A,
        const float* __restrict__ Af, const __bf16* __restrict__ BTg,
        float* __restrict__ Cf, __bf16* __restrict__ Cb,
        const float* __restrict__ avs, const float* __restrict__ avd,
        float* __restrict__ as_, float* __restrict__ ad_,
        int M, int Ntot){
  gemm_body<K,AF32,ALPH,OUTBF>(blockIdx.x, blockIdx.y, A, Af, BTg, Cf, Cb,
                               avs, avd, as_, ad_, M, Ntot);
}

// ---------------- fused: layer-1 GEMM (blocks < gx) || partition phase 1 (blocks >= gx) ----
// Phase 1: per-block LDS counting sort of a 4096-edge chunk into dst-buckets; zero global atomics.
__global__ __launch_bounds__(256) void gemm1_part1_k(
        const float* __restrict__ x, const __bf16* __restrict__ W1T,
        __bf16* __restrict__ hb, const float* __restrict__ a1s,
        const float* __restrict__ a1d, float* __restrict__ as_,
        float* __restrict__ ad_, int M,
        const int* __restrict__ ei, const int* __restrict__ flag, int E,
        int2* __restrict__ eb, int* __restrict__ choff, int* __restrict__ ccnt,
        int gx){
  if ((int)blockIdx.x < gx){
    gemm_body<128,true,true,true>(blockIdx.x, 0, nullptr, x, W1T, nullptr, hb,
                                  a1s, a1d, as_, ad_, M, 128);
    return;
  }
  __shared__ int cnt[NBUCK];
  __shared__ int sc[NBUCK];
  const int tid = threadIdx.x;
  const int blk = (int)blockIdx.x - gx;
  const int c0 = blk * CHUNK;
  const int c1 = min(c0 + CHUNK, E);
  const int f = *flag;
  const long long* e64 = (const long long*)ei;
  cnt[tid] = 0;
  __syncthreads();
  for (int t = c0 + tid; t < c1; t += 256){
    int d = f ? (int)e64[(long)E + t] : ei[(long)E + t];
    atomicAdd(&cnt[d >> 8], 1);                 // LDS
  }
  __syncthreads();
  sc[tid] = cnt[tid];
  __syncthreads();
  for (int d=1; d<NBUCK; d<<=1){
    int v = (tid >= d) ? sc[tid-d] : 0;
    __syncthreads();
    sc[tid] += v;
    __syncthreads();
  }
  const int excl = sc[tid] - cnt[tid];
  __syncthreads();
  sc[tid] = excl;
  choff[blk*NBUCK + tid] = c0 + excl;
  ccnt [blk*NBUCK + tid] = cnt[tid];
  __syncthreads();
  for (int t = c0 + tid; t < c1; t += 256){
    int s, d;
    if (f){ s = (int)e64[t]; d = (int)e64[(long)E + t]; }
    else  { s = ei[t];       d = ei[(long)E + t]; }
    int p = atomicAdd(&sc[d >> 8], 1);          // LDS
    eb[c0 + p] = make_int2(s, d);
  }
}

// ---------------- partition phase 2: one block per bucket; LDS rank -> padded CSR ----
__global__ __launch_bounds__(256) void part2_k(
        const int2* __restrict__ eb, const int* __restrict__ choff,
        const int* __restrict__ ccnt, int B1,
        int* __restrict__ cnt, int* __restrict__ csr,
        int* __restrict__ ovfn, int* __restrict__ ovf, int N){
  __shared__ int lcnt[256];
  const int tid = threadIdx.x;
  const int b = blockIdx.x;
  const int d0 = b << 8;
  lcnt[tid] = 0;
  __syncthreads();
  for (int c = tid; c < B1; c += 256){
    const int off = choff[c*NBUCK + b];
    const int k   = ccnt [c*NBUCK + b];
    for (int j=0; j<k; j++){
      const int2 e = eb[off + j];
      const int r = atomicAdd(&lcnt[e.y - d0], 1);   // LDS
      if (r < CSR_CAP) csr[(size_t)e.y*CSR_CAP + r] = e.x;
      else { int op = atomicAdd(ovfn, 1); ovf[2*op] = e.y; ovf[2*op+1] = e.x; }
    }
  }
  __syncthreads();
  const int d = d0 + tid;
  if (d < N) cnt[d] = lcnt[tid];
}

// ---------------- aggregation: 16-lane groups, 4 nodes/wave, single-pass online softmax ----
// uint4 gathers (dwordx4), f32x2 packed FMA accumulation, compile-time-16 full-chunk path.
template<int F, int ACT>
__global__ __launch_bounds__(256) void aggregate_k(const __bf16* __restrict__ h,
        const float* __restrict__ as, const float* __restrict__ ad,
        const int* __restrict__ cnt, const int* __restrict__ csr,
        const int* __restrict__ ovfn, const int* __restrict__ ovf,
        const float* __restrict__ bias, __bf16* __restrict__ y, int N){
  constexpr int FPL = F/16;            // bf16 features per lane (8 or 4)
  constexpr int DW  = FPL/2;           // dwords per lane (4 or 2)
  __shared__ int2 sw[256];
  const int tid = threadIdx.x;
  const int l = tid & 15;
  const int gbase = tid & 0xF0;
  const int i = blockIdx.x*16 + (tid >> 4);
  if (i >= N) return;
  const int nov = *ovfn;               // 0 in practice

  const int deg = min(cnt[i], CSR_CAP);
  const long b0 = (long)i*CSR_CAP;
  const float adi = ad[i];
  const float e_self = lrelu(as[i] + adi, 0.2f);
  float m = e_self, dsum = 0.f;
  f32x2 acc2[DW];
  #pragma unroll
  for (int d=0; d<DW; d++) acc2[d] = (f32x2){0.f, 0.f};

  union U2 { unsigned u[2]; f32x2 f; };
  auto edge_fma = [&](int sk, float wk){
    if constexpr (DW == 4){
      const uint4 hv = *(const uint4*)(h + (size_t)sk*F + l*FPL);   // 16B, aligned
      U2 t0, t1, t2, t3;
      t0.u[0] = hv.x << 16; t0.u[1] = hv.x & 0xffff0000u;
      t1.u[0] = hv.y << 16; t1.u[1] = hv.y & 0xffff0000u;
      t2.u[0] = hv.z << 16; t2.u[1] = hv.z & 0xffff0000u;
      t3.u[0] = hv.w << 16; t3.u[1] = hv.w & 0xffff0000u;
      acc2[0] += wk * t0.f; acc2[1] += wk * t1.f;
      acc2[2] += wk * t2.f; acc2[3] += wk * t3.f;
    } else {
      const uint2 hv = *(const uint2*)(h + (size_t)sk*F + l*FPL);   // 8B, aligned
      U2 t0, t1;
      t0.u[0] = hv.x << 16; t0.u[1] = hv.x & 0xffff0000u;
      t1.u[0] = hv.y << 16; t1.u[1] = hv.y & 0xffff0000u;
      acc2[0] += wk * t0.f; acc2[1] += wk * t1.f;
    }
  };

  for (int base = 0; base < deg; base += 16){
    const int p = base + l;
    int s = 0; float e = -1e30f;
    if (p < deg){ s = csr[b0 + p]; e = lrelu(as[s] + adi, 0.2f); }
    float cm = e;
    #pragma unroll
    for (int o=8; o; o>>=1) cm = fmaxf(cm, __shfl_xor(cm, o));
    if (cm > m){                       // group-uniform
      const float scv = __expf(m - cm);
      #pragma unroll
      for (int d=0; d<DW; d++) acc2[d] *= scv;
      dsum *= scv; m = cm;
    }
    const float wv = (p < deg) ? __expf(e - m) : 0.f;
    dsum += wv;
    sw[tid] = make_int2(s, __float_as_int(wv));
    const int c = min(16, deg - base);
    if (c == 16){                      // full chunk: no bounds checks, max load batching
      #pragma unroll
      for (int k=0; k<16; k++){
        const int2 sk = sw[gbase + k];
        edge_fma(sk.x, __int_as_float(sk.y));
      }
    } else {
      for (int k=0; k<c; k++){
        const int2 sk = sw[gbase + k];
        edge_fma(sk.x, __int_as_float(sk.y));
      }
    }
  }

  if (nov > 0){                        // spill path: correctness only, never hot
    for (int p=0; p<nov; p++){
      if (ovf[2*p] != i) continue;
      const int s = ovf[2*p+1];
      const float e = lrelu(as[s] + adi, 0.2f);
      if (e > m){
        const float scv = __expf(m - e);
        #pragma unroll
        for (int d=0; d<DW; d++) acc2[d] *= scv;
        dsum *= scv; m = e;
      }
      const float wv = __expf(e - m);
      if (l == 0) dsum += wv;          // counted once per group (group-sum follows)
      edge_fma(s, wv);
    }
  }

  #pragma unroll
  for (int o=8; o; o>>=1) dsum += __shfl_xor(dsum, o);
  const float wself = __expf(e_self - m);
  dsum += wself;
  edge_fma(i, wself);                  // self loop

  const float inv = 1.f / dsum;
  __bf16 ov[FPL];
  #pragma unroll
  for (int j=0; j<FPL; j++){
    float o0 = acc2[j>>1][j&1]*inv + bias[l*FPL + j];
    if (ACT) o0 = lrelu(o0, 0.1f);
    ov[j] = (__bf16)o0;
  }
  if constexpr (FPL == 8) *(bf16x8*)(y + (size_t)i*F + l*FPL) = *(bf16x8*)ov;
  else                    *(uint2*)(y + (size_t)i*F + l*FPL) = *(uint2*)ov;
}

extern "C" void kernel_launch(void* const* d_in, const int* in_sizes, int n_in,
                              void* d_out, int out_size, void* d_ws, size_t ws_size,
                              hipStream_t stream){
  const float* x   = (const float*)d_in[0];
  const int*   ei  = (const int*)d_in[1];
  const float* W1  = (const float*)d_in[2];
  const float* a1s = (const float*)d_in[3];
  const float* a1d = (const float*)d_in[4];
  const float* b1  = (const float*)d_in[5];
  const float* W2  = (const float*)d_in[6];
  const float* a2s = (const float*)d_in[7];
  const float* a2d = (const float*)d_in[8];
  const float* b2  = (const float*)d_in[9];
  const float* W3  = (const float*)d_in[10];
  const float* a3s = (const float*)d_in[11];
  const float* a3d = (const float*)d_in[12];
  const float* b3  = (const float*)d_in[13];
  const float* S   = (const float*)d_in[14];
  float* out = (float*)d_out;            // fp32 output

  const int N = in_sizes[0] / 128;   // 50000
  const int E = in_sizes[1] / 2;     // 800000

  char* w = (char*)d_ws;
  size_t o = 0;
  auto alloc = [&](size_t bytes)->void*{
    void* p = w + o; o += bytes; o = (o + 255) & ~(size_t)255; return p;
  };
  const int B1 = (E + CHUNK - 1) / CHUNK;       // phase-1 blocks (196)
  int*    cnt    = (int*)   alloc((size_t)N*4);
  int*    csr    = (int*)   alloc((size_t)N*CSR_CAP*4);
  int2*   eb     = (int2*)  alloc((size_t)E*8);
  int*    choff  = (int*)   alloc((size_t)B1*NBUCK*4);
  int*    ccnt   = (int*)   alloc((size_t)B1*NBUCK*4);
  int*    ovfn   = (int*)   alloc(4);
  int*    ovf    = (int*)   alloc(65536);
  int*    flag   = (int*)   alloc(4);
  float*  as_    = (float*) alloc((size_t)N*4);
  float*  ad_    = (float*) alloc((size_t)N*4);
  __bf16* hb     = (__bf16*)alloc((size_t)N*128*2);
  __bf16* yb     = (__bf16*)alloc((size_t)N*128*2);
  __bf16* W1T    = (__bf16*)alloc(128*128*2);
  __bf16* W2T    = (__bf16*)alloc(128*128*2);
  __bf16* W3T    = (__bf16*)alloc(64*128*2);
  __bf16* Sb     = (__bf16*)alloc(512*64*2);
  (void)ws_size; (void)n_in; (void)out_size;

  const int gx  = (N + 63) / 64;               // 782 gemm blocks
  const int ab  = (N + 15) / 16;               // aggregate blocks: 16 nodes/block
  const int nbk = (N + 255) / 256;             // phase-2 blocks

  // K1: weight prep + flag detect + ovfn zero
  prep_k<<<288, 256, 0, stream>>>(W1, W2, W3, S, ei, W1T, W2T, W3T, Sb, flag, ovfn);
  // K2: layer-1 GEMM || partition phase 1 (independent halves, overlapped)
  gemm1_part1_k<<<gx + B1, 256, 0, stream>>>(
      x, W1T, hb, a1s, a1d, as_, ad_, N, ei, flag, E, eb, choff, ccnt, gx);
  // K3: partition phase 2 -> padded CSR + cnt
  part2_k<<<nbk, 256, 0, stream>>>(eb, choff, ccnt, B1, cnt, csr, ovfn, ovf, N);
  aggregate_k<128,1><<<ab, 256, 0, stream>>>(hb, as_, ad_, cnt, csr, ovfn, ovf, b1, yb, N);
  // Layer 2
  gemm_k<128,false,true,true><<<dim3(gx,1), 256, 0, stream>>>(
      yb, nullptr, W2T, nullptr, hb, a2s, a2d, as_, ad_, N, 128);
  aggregate_k<128,1><<<ab, 256, 0, stream>>>(hb, as_, ad_, cnt, csr, ovfn, ovf, b2, yb, N);
  // Layer 3 (Ntot = 64)
  gemm_k<128,false,true,true><<<dim3(gx,1), 256, 0, stream>>>(
      yb, nullptr, W3T, nullptr, hb, a3s, a3d, as_, ad_, N, 64);
  aggregate_k<64,0><<<ab, 256, 0, stream>>>(hb, as_, ad_, cnt, csr, ovfn, ovf, b3, yb, N);
  // Final projection: out[N,512] = y[N,64] @ S^T  (BT = S itself, cast to bf16)
  gemm_k<64,false,false,false><<<dim3(gx,4), 256, 0, stream>>>(
      yb, nullptr, Sb, out, nullptr, nullptr, nullptr, nullptr, nullptr, N, 512);
}